// Round 1
// baseline (610.204 us; speedup 1.0000x reference)
//
#include <hip/hip_runtime.h>
#include <hip/hip_bf16.h>

// Sizes (from reference):
// B=1024, n_el=32, n_up=16, n_ion=8, d_one=256, d_two=32, d_ion=64, d_elion=32, emb=64
// feats: (B,32,928) -> 30,408,704 floats; el_el_mult: (B,32,32,64) -> 67,108,864 floats
// feats cols: [0:256 h_one][256:512 tile_up][512:768 tile_dn][768:800 f_pairs_up]
//             [800:832 f_pairs_dn][832:896 el_el][896:928 el_ion]

#define FEATS_ELEMS 30408704ull
#define FD 928

// ---------------- Kernel 1: per-batch h_one features + h_mapped + h_ion_mapped ----
__global__ __launch_bounds__(256) void sf_k1(
    const float* __restrict__ h_one,   // (B,32,256)
    const float* __restrict__ h_ion,   // (B,8,64)
    const float* __restrict__ W_hmap,  // (256,64)
    const float* __restrict__ b_hmap,  // (64)
    const float* __restrict__ W_ion,   // (64,32)
    const float* __restrict__ b_ion,   // (32)
    float* __restrict__ feats,         // (B,32,928)
    float* __restrict__ hmap_ws,       // (B,32,64)
    float* __restrict__ hion_ws)       // (B,8,32)
{
    __shared__ float s_hone[32 * 256];   // 32 KB
    const int b = blockIdx.x;
    const int t = threadIdx.x;           // 0..255 — one column d of h_one

    // ---- phase 1: copy h_one -> feats, compute spin means, broadcast tiles ----
    const float* hb = h_one + (size_t)b * 32 * 256;
    float su = 0.f, sd = 0.f;
    #pragma unroll
    for (int i = 0; i < 32; ++i) {
        float v = hb[i * 256 + t];
        s_hone[i * 256 + t] = v;
        if (i < 16) su += v; else sd += v;
        feats[(size_t)(b * 32 + i) * FD + t] = v;
    }
    su *= (1.f / 16.f);
    sd *= (1.f / 16.f);
    #pragma unroll
    for (int i = 0; i < 32; ++i) {
        size_t row = (size_t)(b * 32 + i) * FD;
        feats[row + 256 + t] = su;
        feats[row + 512 + t] = sd;
    }
    __syncthreads();

    // ---- phase 2: h_mapped = tanh(h_one @ W_hmap + b_hmap) ----
    // thread t -> fixed output col e = t&63, rows i = r*4 + (t>>6), r=0..7
    {
        const int e = t & 63;
        const int isub = t >> 6;  // 0..3
        float acc[8];
        const float bh = b_hmap[e];
        #pragma unroll
        for (int r = 0; r < 8; ++r) acc[r] = bh;
        for (int k = 0; k < 256; ++k) {
            float w = W_hmap[k * 64 + e];
            #pragma unroll
            for (int r = 0; r < 8; ++r)
                acc[r] += s_hone[(r * 4 + isub) * 256 + k] * w;
        }
        #pragma unroll
        for (int r = 0; r < 8; ++r) {
            int i = r * 4 + isub;
            hmap_ws[(size_t)(b * 32 + i) * 64 + e] = tanhf(acc[r]);
        }
    }

    // ---- phase 3: h_ion_mapped = tanh(h_ion @ W_ion + b_ion), 8x32 outputs ----
    {
        const int a  = t >> 5;   // ion 0..7
        const int kk = t & 31;   // out col 0..31
        float d = b_ion[kk];
        const float* hi = h_ion + (size_t)b * 8 * 64 + a * 64;
        #pragma unroll 8
        for (int k2 = 0; k2 < 64; ++k2) d += hi[k2] * W_ion[k2 * 32 + kk];
        hion_ws[(size_t)b * 256 + a * 32 + kk] = tanhf(d);
    }
}

// ---------------- Kernel 2: el_el_mult + el_el + f_pairs + el_ion ----------------
// grid = B*8 blocks; each block handles 4 electrons i (one wave each).
__global__ __launch_bounds__(256) void sf_k2(
    const float* __restrict__ h_el_el,  // (B,32,32,32)
    const float* __restrict__ h_el_ion, // (B,32,8,32)
    const float* __restrict__ W_wsame,  // (32,64)
    const float* __restrict__ b_wsame,  // (64)
    const float* __restrict__ W_wdiff,  // (32,64)
    const float* __restrict__ b_wdiff,  // (64)
    const float* __restrict__ hmap_ws,  // (B,32,64)
    const float* __restrict__ hion_ws,  // (B,8,32)
    float* __restrict__ feats,          // (B,32,928)
    float* __restrict__ mult_out)       // (B,32,32,64)
{
    __shared__ float s_hee[4 * 1024];   // 4 electrons x (32 j x 32 k) = 16 KB
    __shared__ float s_hmap[2048];      // (32 j x 64 e) = 8 KB
    const int b  = blockIdx.x >> 3;
    const int i0 = (blockIdx.x & 7) * 4;
    const int t  = threadIdx.x;

    // cooperative staging
    const float* src = h_el_el + (size_t)(b * 32 + i0) * 1024;
    #pragma unroll
    for (int r = 0; r < 16; ++r) s_hee[r * 256 + t] = src[r * 256 + t];
    const float* hm = hmap_ws + (size_t)b * 2048;
    #pragma unroll
    for (int r = 0; r < 8; ++r) s_hmap[r * 256 + t] = hm[r * 256 + t];

    // per-thread weight columns (wave-redundant load, L1/L2-hot)
    const int e = t & 63;
    const int w = t >> 6;
    const int i = i0 + w;
    float wsc[32], wdc[32];
    #pragma unroll
    for (int k = 0; k < 32; ++k) {
        wsc[k] = W_wsame[k * 64 + e];
        wdc[k] = W_wdiff[k * 64 + e];
    }
    const float bs = b_wsame[e];
    const float bd = b_wdiff[e];
    __syncthreads();

    const float* hee = s_hee + w * 1024;
    const bool iup = (i < 16);
    float accsum = 0.f;
    float* mrow = mult_out + (size_t)(b * 32 + i) * 2048;

    for (int j = 0; j < 32; ++j) {
        const bool same = (iup == (j < 16));   // wave-uniform branch
        float d;
        if (same) {
            d = bs;
            #pragma unroll
            for (int k = 0; k < 32; ++k) d += hee[j * 32 + k] * wsc[k];
        } else {
            d = bd;
            #pragma unroll
            for (int k = 0; k < 32; ++k) d += hee[j * 32 + k] * wdc[k];
        }
        float m = tanhf(d) * s_hmap[j * 64 + e];
        mrow[j * 64 + e] = m;
        accsum += m;
    }

    const size_t frow = (size_t)(b * 32 + i) * FD;
    feats[frow + 832 + e] = accsum * (1.f / 16.f);

    // f_pairs: e<32 -> up col e over j=0..15; e>=32 -> dn col e-32 over j=16..31
    {
        const int k = e & 31;
        const int jbase = (e < 32) ? 0 : 16;
        float s = 0.f;
        #pragma unroll
        for (int j = 0; j < 16; ++j) s += hee[(jbase + j) * 32 + k];
        feats[frow + 768 + e] = s * (1.f / 16.f);
    }

    // el_ion: 32 cols, lanes e<32
    if (e < 32) {
        const float* hei = h_el_ion + (size_t)(b * 32 + i) * 256;
        const float* him = hion_ws + (size_t)b * 256;
        float s = 0.f;
        #pragma unroll
        for (int a = 0; a < 8; ++a) s += hei[a * 32 + e] * him[a * 32 + e];
        feats[frow + 896 + e] = s * (1.f / 8.f);
    }
}

extern "C" void kernel_launch(void* const* d_in, const int* in_sizes, int n_in,
                              void* d_out, int out_size, void* d_ws, size_t ws_size,
                              hipStream_t stream) {
    const float* h_one    = (const float*)d_in[0];
    const float* h_ion    = (const float*)d_in[1];
    const float* h_el_el  = (const float*)d_in[2];
    const float* h_el_ion = (const float*)d_in[3];
    const float* W_hmap   = (const float*)d_in[4];
    const float* b_hmap   = (const float*)d_in[5];
    const float* W_wsame  = (const float*)d_in[6];
    const float* b_wsame  = (const float*)d_in[7];
    const float* W_wdiff  = (const float*)d_in[8];
    const float* b_wdiff  = (const float*)d_in[9];
    const float* W_ion    = (const float*)d_in[10];
    const float* b_ion    = (const float*)d_in[11];

    float* feats    = (float*)d_out;
    float* mult_out = feats + FEATS_ELEMS;

    float* hmap_ws = (float*)d_ws;                 // 1024*32*64 = 2,097,152 floats
    float* hion_ws = hmap_ws + 1024 * 32 * 64;     // 1024*8*32  =   262,144 floats

    sf_k1<<<1024, 256, 0, stream>>>(h_one, h_ion, W_hmap, b_hmap, W_ion, b_ion,
                                    feats, hmap_ws, hion_ws);
    sf_k2<<<1024 * 8, 256, 0, stream>>>(h_el_el, h_el_ion, W_wsame, b_wsame,
                                        W_wdiff, b_wdiff, hmap_ws, hion_ws,
                                        feats, mult_out);
}

// Round 2
// 566.247 us; speedup vs baseline: 1.0776x; 1.0776x over previous
//
#include <hip/hip_runtime.h>
#include <hip/hip_bf16.h>

// B=1024, n_el=32, n_up=16, n_ion=8, d_one=256, d_two=32, d_ion=64, d_elion=32, emb=64
// feats: (B,32,928); el_el_mult: (B,32,32,64)
// feats cols: [0:256 h_one][256:512 tile_up][512:768 tile_dn][768:800 f_pairs_up]
//             [800:832 f_pairs_dn][832:896 el_el][896:928 el_ion]

#define FEATS_ELEMS 30408704ull
#define FD 928

typedef __attribute__((ext_vector_type(8))) short bfrag8;   // 8 bf16 = 4 VGPR
typedef __attribute__((ext_vector_type(4))) float vf4;
typedef __attribute__((ext_vector_type(4))) unsigned short us4;

static __device__ __forceinline__ unsigned short f2bf(float f) {
    unsigned int u = __builtin_bit_cast(unsigned int, f);
    unsigned int r = (u + 0x7FFFu + ((u >> 16) & 1u)) >> 16;   // RNE, finite inputs
    return (unsigned short)r;
}
static __device__ __forceinline__ float bf2f(unsigned short u) {
    unsigned int v = ((unsigned int)u) << 16;
    return __builtin_bit_cast(float, v);
}
// tanh(x) = 1 - 2/(e^{2x}+1); exp->inf => 1, exp->0 => -1 (branchless, correct asymptotes)
static __device__ __forceinline__ float fast_tanh(float x) {
    float e = __expf(2.f * x);
    return 1.f - 2.f * __builtin_amdgcn_rcpf(e + 1.f);
}

// ---------------- Kernel 1: h_one feats + h_mapped (MFMA) + h_ion_mapped ----------
__global__ __launch_bounds__(256) void sf_k1(
    const float* __restrict__ h_one,   // (B,32,256)
    const float* __restrict__ h_ion,   // (B,8,64)
    const float* __restrict__ W_hmap,  // (256,64)
    const float* __restrict__ b_hmap,  // (64)
    const float* __restrict__ W_ion,   // (64,32)
    const float* __restrict__ b_ion,   // (32)
    float* __restrict__ feats,
    float* __restrict__ hmap_ws,       // (B,32,64)
    float* __restrict__ hion_ws)       // (B,8,32)
{
    __shared__ unsigned short s_hbf[32 * 264];   // h_one as bf16, padded stride 264
    const int b = blockIdx.x;
    const int t = threadIdx.x;

    // phase 1: copy h_one -> feats, spin means, bf16 stage
    const float* hb = h_one + (size_t)b * 8192;
    float su = 0.f, sd = 0.f;
    #pragma unroll
    for (int i = 0; i < 32; ++i) {
        float v = hb[i * 256 + t];
        s_hbf[i * 264 + t] = f2bf(v);
        if (i < 16) su += v; else sd += v;
        feats[(size_t)(b * 32 + i) * FD + t] = v;
    }
    su *= (1.f / 16.f);
    sd *= (1.f / 16.f);
    #pragma unroll
    for (int i = 0; i < 32; ++i) {
        size_t row = (size_t)(b * 32 + i) * FD;
        feats[row + 256 + t] = su;
        feats[row + 512 + t] = sd;
    }

    // phase 3: h_ion_mapped (cheap, before barrier)
    {
        const int ai = t >> 5, kk = t & 31;
        float d = b_ion[kk];
        const float* hi = h_ion + (size_t)b * 512 + ai * 64;
        #pragma unroll 8
        for (int k2 = 0; k2 < 64; ++k2) d += hi[k2] * W_ion[k2 * 32 + kk];
        hion_ws[(size_t)b * 256 + ai * 32 + kk] = fast_tanh(d);
    }
    __syncthreads();

    // phase 2: h_mapped = tanh(h_one @ W_hmap + b) via mfma 16x16x32 bf16
    const int lane  = t & 63;
    const int nt    = t >> 6;        // wave -> 16-col tile
    const int col15 = lane & 15;
    const int quad  = lane >> 4;
    const int col   = nt * 16 + col15;

    float bh = b_hmap[col];
    vf4 acc0 = {bh, bh, bh, bh};     // rows 0..15
    vf4 acc1 = acc0;                 // rows 16..31
    #pragma unroll
    for (int ks = 0; ks < 8; ++ks) {
        bfrag8 bf;
        #pragma unroll
        for (int ii = 0; ii < 8; ++ii) {
            int k = ks * 32 + quad * 8 + ii;
            bf[ii] = (short)f2bf(W_hmap[k * 64 + col]);
        }
        const bfrag8 a0 = *(const bfrag8*)(s_hbf + col15 * 264 + ks * 32 + quad * 8);
        const bfrag8 a1 = *(const bfrag8*)(s_hbf + (16 + col15) * 264 + ks * 32 + quad * 8);
        acc0 = __builtin_amdgcn_mfma_f32_16x16x32_bf16(a0, bf, acc0, 0, 0, 0);
        acc1 = __builtin_amdgcn_mfma_f32_16x16x32_bf16(a1, bf, acc1, 0, 0, 0);
    }
    #pragma unroll
    for (int r = 0; r < 4; ++r) {
        int j0 = quad * 4 + r;       // C/D: row = quad*4+reg, col = lane&15
        hmap_ws[(size_t)(b * 32 + j0) * 64 + col]      = fast_tanh(acc0[r]);
        hmap_ws[(size_t)(b * 32 + 16 + j0) * 64 + col] = fast_tanh(acc1[r]);
    }
}

// ---------------- Kernel 2: mult + el_el + f_pairs + el_ion (MFMA) ----------------
// grid = B*8 blocks; wave wv handles electron i = i0 + wv.
__global__ __launch_bounds__(256) void sf_k2(
    const float* __restrict__ h_el_el,  // (B,32,32,32)
    const float* __restrict__ h_el_ion, // (B,32,8,32)
    const float* __restrict__ W_wsame,  // (32,64)
    const float* __restrict__ b_wsame,  // (64)
    const float* __restrict__ W_wdiff,  // (32,64)
    const float* __restrict__ b_wdiff,  // (64)
    const float* __restrict__ hmap_ws,  // (B,32,64)
    const float* __restrict__ hion_ws,  // (B,8,32)
    float* __restrict__ feats,
    float* __restrict__ mult_out)       // (B,32,32,64)
{
    __shared__ unsigned short s_hee[4 * 32 * 40];  // 4 el x 32 j x 32 k bf16, stride 40
    __shared__ float s_hmap[32 * 68];              // 32 j x 64 e fp32, stride 68
    const int b  = blockIdx.x >> 3;
    const int i0 = (blockIdx.x & 7) * 4;
    const int t  = threadIdx.x;

    // stage hee (fp32 -> bf16) and hmap
    {
        const float* src = h_el_el + (size_t)(b * 32 + i0) * 1024;
        #pragma unroll
        for (int r = 0; r < 4; ++r) {
            int c = r * 256 + t;                 // float4 chunk id
            vf4 v = ((const vf4*)src)[c];
            int g = 4 * c;
            int row = g >> 5;                    // (il*32 + j)
            int k = g & 31;
            us4 wq = { f2bf(v[0]), f2bf(v[1]), f2bf(v[2]), f2bf(v[3]) };
            *(us4*)(s_hee + row * 40 + k) = wq;
        }
        const float* hm = hmap_ws + (size_t)b * 2048;
        #pragma unroll
        for (int r = 0; r < 2; ++r) {
            int c = r * 256 + t;
            vf4 v = ((const vf4*)hm)[c];
            int g = 4 * c;
            int row = g >> 6;
            int cc = g & 63;
            *(vf4*)(s_hmap + row * 68 + cc) = v;
        }
    }

    const int lane  = t & 63;
    const int wv    = t >> 6;
    const int i     = i0 + wv;
    const int col15 = lane & 15;
    const int quad  = lane >> 4;

    // B-frags: Wsame/Wdiff, 4 N-tiles each, from global (L1/L2-hot)
    bfrag8 bs_fr[4], bd_fr[4];
    #pragma unroll
    for (int nt = 0; nt < 4; ++nt) {
        #pragma unroll
        for (int ii = 0; ii < 8; ++ii) {
            int k = quad * 8 + ii;
            int n = nt * 16 + col15;
            bs_fr[nt][ii] = (short)f2bf(W_wsame[k * 64 + n]);
            bd_fr[nt][ii] = (short)f2bf(W_wdiff[k * 64 + n]);
        }
    }
    __syncthreads();

    const unsigned short* hrow = s_hee + wv * 1280;   // this electron's 32x40 tile
    const bfrag8 a_up = *(const bfrag8*)(hrow + col15 * 40 + quad * 8);
    const bfrag8 a_dn = *(const bfrag8*)(hrow + (16 + col15) * 40 + quad * 8);

    const bool iup = (i < 16);
    float* mrow = mult_out + (size_t)(b * 32 + i) * 2048;
    const size_t frow = (size_t)(b * 32 + i) * FD;

    #pragma unroll
    for (int nt = 0; nt < 4; ++nt) {
        const int col = nt * 16 + col15;
        float vbs = b_wsame[col], vbd = b_wdiff[col];
        float bu = iup ? vbs : vbd;
        float bd = iup ? vbd : vbs;
        bfrag8 fu = iup ? bs_fr[nt] : bd_fr[nt];   // j<16 rows weight
        bfrag8 fd = iup ? bd_fr[nt] : bs_fr[nt];   // j>=16 rows weight
        vf4 cu = {bu, bu, bu, bu};
        vf4 cd = {bd, bd, bd, bd};
        cu = __builtin_amdgcn_mfma_f32_16x16x32_bf16(a_up, fu, cu, 0, 0, 0);
        cd = __builtin_amdgcn_mfma_f32_16x16x32_bf16(a_dn, fd, cd, 0, 0, 0);
        float s = 0.f;
        #pragma unroll
        for (int r = 0; r < 4; ++r) {
            int ju = quad * 4 + r;
            float mu = fast_tanh(cu[r]) * s_hmap[ju * 68 + col];
            mrow[ju * 64 + col] = mu;
            int jd = 16 + ju;
            float md = fast_tanh(cd[r]) * s_hmap[jd * 68 + col];
            mrow[jd * 64 + col] = md;
            s += mu + md;
        }
        s += __shfl_xor(s, 16, 64);
        s += __shfl_xor(s, 32, 64);
        if (quad == 0) feats[frow + 832 + col] = s * (1.f / 16.f);
    }

    // f_pairs from bf16 staged hee (err ~4e-3 << 0.108 threshold)
    {
        const int k = lane & 31;
        const int jb = (lane < 32) ? 0 : 16;
        float s = 0.f;
        #pragma unroll
        for (int j = 0; j < 16; ++j) s += bf2f(hrow[(jb + j) * 40 + k]);
        feats[frow + 768 + lane] = s * (1.f / 16.f);
    }

    // el_ion
    if (lane < 32) {
        const float* hei = h_el_ion + (size_t)(b * 32 + i) * 256;
        const float* him = hion_ws + (size_t)b * 256;
        float s = 0.f;
        #pragma unroll
        for (int a = 0; a < 8; ++a) s += hei[a * 32 + lane] * him[a * 32 + lane];
        feats[frow + 896 + lane] = s * (1.f / 8.f);
    }
}

extern "C" void kernel_launch(void* const* d_in, const int* in_sizes, int n_in,
                              void* d_out, int out_size, void* d_ws, size_t ws_size,
                              hipStream_t stream) {
    const float* h_one    = (const float*)d_in[0];
    const float* h_ion    = (const float*)d_in[1];
    const float* h_el_el  = (const float*)d_in[2];
    const float* h_el_ion = (const float*)d_in[3];
    const float* W_hmap   = (const float*)d_in[4];
    const float* b_hmap   = (const float*)d_in[5];
    const float* W_wsame  = (const float*)d_in[6];
    const float* b_wsame  = (const float*)d_in[7];
    const float* W_wdiff  = (const float*)d_in[8];
    const float* b_wdiff  = (const float*)d_in[9];
    const float* W_ion    = (const float*)d_in[10];
    const float* b_ion    = (const float*)d_in[11];

    float* feats    = (float*)d_out;
    float* mult_out = feats + FEATS_ELEMS;

    float* hmap_ws = (float*)d_ws;                 // 1024*32*64 floats
    float* hion_ws = hmap_ws + 1024 * 32 * 64;     // 1024*8*32 floats

    sf_k1<<<1024, 256, 0, stream>>>(h_one, h_ion, W_hmap, b_hmap, W_ion, b_ion,
                                    feats, hmap_ws, hion_ws);
    sf_k2<<<1024 * 8, 256, 0, stream>>>(h_el_el, h_el_ion, W_wsame, b_wsame,
                                        W_wdiff, b_wdiff, hmap_ws, hion_ws,
                                        feats, mult_out);
}